// Round 12
// baseline (524.566 us; speedup 1.0000x reference)
//
#include <hip/hip_runtime.h>

#define SEQ 128
#define HID 32
#define TPB2 128  // 2 waves; wave = unit-half (t1); 32 nodes/block (2 groups of 16)
#define XS 40     // LDS row stride in shorts: 80B = 5*16B (16B-aligned b128 rows)

typedef __attribute__((ext_vector_type(8))) short short8;   // 8 bf16 = 4 VGPR
typedef __attribute__((ext_vector_type(4))) float floatx4;  // MFMA acc

// ---------------- GCN prep (identical to round-11 verified version) ----------------

__global__ void count_kernel(const int* __restrict__ idx, int E, int* __restrict__ cnt) {
    int e = (blockIdx.x * blockDim.x + threadIdx.x) * 4;
    if (((E & 3) == 0) && e + 3 < E) {
        int4 d = *(const int4*)(idx + E + e);   // 16B aligned: E%4==0, e%4==0
        atomicAdd(&cnt[d.x], 1);
        atomicAdd(&cnt[d.y], 1);
        atomicAdd(&cnt[d.z], 1);
        atomicAdd(&cnt[d.w], 1);
    } else {
        int lim = min(e + 4, E);
        for (int k = e; k < lim; ++k) atomicAdd(&cnt[idx[E + k]], 1);
    }
}

// Fixed-point pack: q = rn(v * 2^21), biased +2^26 per 32b field -> every added term
// positive and < 2^26.2, no cross-field carry up to ~56 adds. ONE u64 atomic per
// edge; dinv[src] computed inline from the deg gather (scatter is atomic-rate-bound).
__device__ __forceinline__ unsigned long long pk2(float xx, float yy, float dv) {
    int qx = __float2int_rn(xx * dv * 2097152.0f);
    int qy = __float2int_rn(yy * dv * 2097152.0f);
    return ((unsigned long long)(unsigned)(qx + (1 << 26)) << 32) |
           (unsigned)(qy + (1 << 26));
}

__global__ void scatter_pk_kernel(const int* __restrict__ idx, int E,
                                  const float2* __restrict__ x2,
                                  const int* __restrict__ deg,
                                  unsigned long long* __restrict__ aggP) {
    int e = (blockIdx.x * blockDim.x + threadIdx.x) * 4;
    if (((E & 3) == 0) && e + 3 < E) {
        int4 s = *(const int4*)(idx + e);
        int4 d = *(const int4*)(idx + E + e);
        float2 v0 = x2[s.x];
        float2 v1 = x2[s.y];
        float2 v2 = x2[s.z];
        float2 v3 = x2[s.w];
        float dv0 = rsqrtf((float)deg[s.x] + 1.0f);
        float dv1 = rsqrtf((float)deg[s.y] + 1.0f);
        float dv2 = rsqrtf((float)deg[s.z] + 1.0f);
        float dv3 = rsqrtf((float)deg[s.w] + 1.0f);
        atomicAdd(&aggP[d.x], pk2(v0.x, v0.y, dv0));
        atomicAdd(&aggP[d.y], pk2(v1.x, v1.y, dv1));
        atomicAdd(&aggP[d.z], pk2(v2.x, v2.y, dv2));
        atomicAdd(&aggP[d.w], pk2(v3.x, v3.y, dv3));
    } else {
        int lim = min(e + 4, E);
        for (int k = e; k < lim; ++k) {
            int s = idx[k];
            int d = idx[E + k];
            float2 v = x2[s];
            float dv = rsqrtf((float)deg[s] + 1.0f);
            atomicAdd(&aggP[d], pk2(v.x, v.y, dv));
        }
    }
}

// -------- MFMA LSTM: swapped-operand, TWO interleaved 16-node groups per wave --------
// r11 structure (verified, 201.6 us) with the latency holes (23% no-issue at 2.44
// waves/SIMD, grid-capped TLP) filled by ILP: each wave runs groups A (nodes n) and
// B (nodes 16+n). W-frags (64 VGPR) + all constants SHARED between groups; only
// state duplicates (~+50 VGPR). Per step: 48 MFMAs as 8 independent 4-wide chains
// (A/B alternate -> sibling group covers each chain's dep latency), acts for both
// groups, ONE barrier per step = per-node sync cost halved. 625 blocks, 3 blocks/CU
// (53.8 KB LDS <= 54.6), one generation. Exchange patterns/parity identical to r11.

__device__ __forceinline__ float sg(float y) {       // sigmoid, exp2-prescaled input
    return __builtin_amdgcn_rcpf(1.0f + __builtin_amdgcn_exp2f(-y));
}
__device__ __forceinline__ float tanh_f(float x) {   // unscaled input
    return fmaf(__builtin_amdgcn_rcpf(1.0f + __expf(-2.0f * x)), 2.0f, -1.0f);
}
// truncation split: f = hi + lo (~2^-16 rel); 3-term MFMA keeps fp32-like precision
__device__ __forceinline__ void fsplit(float f, short& hi, short& lo) {
    unsigned u = __float_as_uint(f);
    hi = (short)(u >> 16);
    float r = f - __uint_as_float(u & 0xFFFF0000u);
    lo = (short)(__float_as_uint(r) >> 16);
}
// pair split via v_perm_b32 (verified r9-r11): hi word = (hi16(b)<<16)|hi16(a)
__device__ __forceinline__ void fsplit2(float a, float b, unsigned& hi, unsigned& lo) {
    unsigned ta = __float_as_uint(a) & 0xFFFF0000u;
    unsigned tb = __float_as_uint(b) & 0xFFFF0000u;
    float ra = a - __uint_as_float(ta);
    float rb = b - __uint_as_float(tb);
    hi = __builtin_amdgcn_perm(__float_as_uint(b), __float_as_uint(a), 0x07060302u);
    lo = __builtin_amdgcn_perm(__float_as_uint(rb), __float_as_uint(ra), 0x07060302u);
}

__global__ __launch_bounds__(TPB2, 2) void lstm_sw4_kernel(
    const float2* __restrict__ x2,
    const unsigned long long* __restrict__ aggP, const int* __restrict__ deg,
    int N,
    const float* __restrict__ gcn_W, const float* __restrict__ gcn_b,
    const float* __restrict__ w_ih, const float* __restrict__ w_hh,
    const float* __restrict__ b_ih, const float* __restrict__ b_hh,
    const float* __restrict__ fc_W, const float* __restrict__ fc_b,
    float* __restrict__ out) {
    __shared__ float2 ubuf[32][SEQ + 1];                  // 33.0 KB; col 128 = zero pad
    __shared__ __align__(16) short hhb[2][32][XS];        // h hi [parity][node][unit]
    __shared__ __align__(16) short hlb[2][32][XS];        // h lo
    __shared__ __align__(16) short xgh[2][32][XS];        // xg hi
    __shared__ __align__(16) short xgl[2][32][XS];        // xg lo
    __shared__ float fcp[2][32];

    const int tid = threadIdx.x;
    const int t1 = tid >> 6;       // wave id == unit-half
    const int lane = tid & 63;
    const int n = lane & 15;       // group-A node / C-col (unit) / B-col (gate-row)
    const int q = lane >> 4;       // k-slice / C-row-group
    const int base = blockIdx.x * 32;

    // ---- stage u[node][t] = dv*(agg + x*dv) into LDS (coalesced, 32 iters) ----
    {
        const float2* xb = x2 + (size_t)base * SEQ;
        const unsigned long long* apb = aggP + (size_t)base * SEQ;
        const int* dgb = deg + (size_t)base * SEQ;
        const int lim = min(32 * SEQ, (N - base) * SEQ);
        for (int i = tid; i < 32 * SEQ; i += TPB2) {
            float2 v = make_float2(0.f, 0.f);
            if (i < lim) {
                int dg = dgb[i];
                float dv = rsqrtf((float)dg + 1.0f);
                float2 xx = xb[i];
                unsigned long long pk = apb[i];
                unsigned bias = (unsigned)dg * 67108864u;  // deg * 2^26
                float ax = (float)((int)((unsigned)(pk >> 32) - bias)) * (1.0f / 2097152.0f);
                float ay = (float)((int)((unsigned)pk - bias)) * (1.0f / 2097152.0f);
                v = make_float2(dv * fmaf(xx.x, dv, ax), dv * fmaf(xx.y, dv, ay));
            }
            ubuf[i >> 7][i & 127] = v;
        }
        if (tid < 32) ubuf[tid][SEQ] = make_float2(0.f, 0.f);
        // zero h parity-0 buffers (read at t=0): 32*40/2 = 640 dwords each
        for (int i = tid; i < 640; i += TPB2) {
            ((int*)hhb[0])[i] = 0;
            ((int*)hlb[0])[i] = 0;
        }
    }

    // ---- W B-frags: 4 gate-tiles for unit-half t1 (SHARED by both groups) ----
    short8 WiH[4], WiL[4], WhH[4], WhL[4];
    floatx4 biasv[4];
    #pragma unroll
    for (int g = 0; g < 4; ++g) {
        const float gsc = (g == 2) ? 2.8853900817779268f : 1.4426950408889634f;
        const int arow = g * 32 + 16 * t1 + n;   // B-frag col index = lane&15
        const float* wi = w_ih + arow * HID + 8 * q;
        const float* wh = w_hh + arow * HID + 8 * q;
        #pragma unroll
        for (int j = 0; j < 8; ++j) {
            short h16, l16;
            fsplit(wi[j] * gsc, h16, l16); WiH[g][j] = h16; WiL[g][j] = l16;
            fsplit(wh[j] * gsc, h16, l16); WhH[g][j] = h16; WhL[g][j] = l16;
        }
        const float bb = (b_ih[arow] + b_hh[arow]) * gsc;   // C-col bias: same all rows
        biasv[g] = (floatx4){bb, bb, bb, bb};
    }

    // ---- GCN consts for this lane's OWN xg units: uo = 16*t1 + 4*q + k (shared) ----
    float wgo0[4], wgo1[4], gbo[4];
    #pragma unroll
    for (int k = 0; k < 4; ++k) {
        const int uo = 16 * t1 + 4 * q + k;
        wgo0[k] = gcn_W[uo];
        wgo1[k] = gcn_W[HID + uo];
        gbo[k] = gcn_b[uo];
    }
    const float fcw = fc_W[16 * t1 + n];   // lane's output unit (both groups)

    float cA[4] = {0.f, 0.f, 0.f, 0.f}, hoA[4] = {0.f, 0.f, 0.f, 0.f};
    float cB[4] = {0.f, 0.f, 0.f, 0.f}, hoB[4] = {0.f, 0.f, 0.f, 0.f};

// own-unit xg for both groups at time TT -> parity PAR (writes at rows n and 16+n)
#define OWN_XG2(PAR, TT)                                                          \
    {                                                                             \
        float2 ua = ubuf[n][TT];                                                  \
        float2 ub = ubuf[16 + n][TT];                                             \
        float ga[4], gb[4];                                                       \
        _Pragma("unroll") for (int k = 0; k < 4; ++k) {                           \
            ga[k] = fmaxf(fmaf(ua.x, wgo0[k], fmaf(ua.y, wgo1[k], gbo[k])), 0.f); \
            gb[k] = fmaxf(fmaf(ub.x, wgo0[k], fmaf(ub.y, wgo1[k], gbo[k])), 0.f); \
        }                                                                         \
        unsigned h0, l0, h1, l1;                                                  \
        fsplit2(ga[0], ga[1], h0, l0);                                            \
        fsplit2(ga[2], ga[3], h1, l1);                                            \
        *(uint2*)&xgh[PAR][n][16 * t1 + 4 * q] = make_uint2(h0, h1);              \
        *(uint2*)&xgl[PAR][n][16 * t1 + 4 * q] = make_uint2(l0, l1);              \
        fsplit2(gb[0], gb[1], h0, l0);                                            \
        fsplit2(gb[2], gb[3], h1, l1);                                            \
        *(uint2*)&xgh[PAR][16 + n][16 * t1 + 4 * q] = make_uint2(h0, h1);         \
        *(uint2*)&xgl[PAR][16 + n][16 * t1 + 4 * q] = make_uint2(l0, l1);         \
    }

    __syncthreads();   // ubuf + h-zero staged (both waves)
    OWN_XG2(0, 0);     // xg(0) -> parity 0
    __syncthreads();   // xg(0) visible

// One step, compile-time parity P: reads h(t-1)+xg(t) of BOTH groups from buf P,
// writes h(t)+xg(t+1) to buf P^1, ONE barrier. 48 MFMAs as 8 independent 4-wide
// chains (A/B blocks alternate -> dep latency covered by the sibling group).
#define LSTM_STEP2(P, TT)                                                                     \
    do {                                                                                      \
        const short8 xhA = *(const short8*)&xgh[P][n][8 * q];                                 \
        const short8 xlA = *(const short8*)&xgl[P][n][8 * q];                                 \
        const short8 hhA = *(const short8*)&hhb[P][n][8 * q];                                 \
        const short8 hlA = *(const short8*)&hlb[P][n][8 * q];                                 \
        const short8 xhB = *(const short8*)&xgh[P][16 + n][8 * q];                            \
        const short8 xlB = *(const short8*)&xgl[P][16 + n][8 * q];                            \
        const short8 hhB = *(const short8*)&hhb[P][16 + n][8 * q];                            \
        const short8 hlB = *(const short8*)&hlb[P][16 + n][8 * q];                            \
        floatx4 aA[4], aB[4];                                                                 \
        __builtin_amdgcn_s_setprio(1);                                                        \
        _Pragma("unroll") for (int g = 0; g < 4; ++g)                                         \
            aA[g] = __builtin_amdgcn_mfma_f32_16x16x32_bf16(xhA, WiH[g], biasv[g], 0, 0, 0);  \
        _Pragma("unroll") for (int g = 0; g < 4; ++g)                                         \
            aB[g] = __builtin_amdgcn_mfma_f32_16x16x32_bf16(xhB, WiH[g], biasv[g], 0, 0, 0);  \
        _Pragma("unroll") for (int g = 0; g < 4; ++g)                                         \
            aA[g] = __builtin_amdgcn_mfma_f32_16x16x32_bf16(xhA, WiL[g], aA[g], 0, 0, 0);     \
        _Pragma("unroll") for (int g = 0; g < 4; ++g)                                         \
            aB[g] = __builtin_amdgcn_mfma_f32_16x16x32_bf16(xhB, WiL[g], aB[g], 0, 0, 0);     \
        _Pragma("unroll") for (int g = 0; g < 4; ++g)                                         \
            aA[g] = __builtin_amdgcn_mfma_f32_16x16x32_bf16(xlA, WiH[g], aA[g], 0, 0, 0);     \
        _Pragma("unroll") for (int g = 0; g < 4; ++g)                                         \
            aB[g] = __builtin_amdgcn_mfma_f32_16x16x32_bf16(xlB, WiH[g], aB[g], 0, 0, 0);     \
        _Pragma("unroll") for (int g = 0; g < 4; ++g)                                         \
            aA[g] = __builtin_amdgcn_mfma_f32_16x16x32_bf16(hhA, WhH[g], aA[g], 0, 0, 0);     \
        _Pragma("unroll") for (int g = 0; g < 4; ++g)                                         \
            aB[g] = __builtin_amdgcn_mfma_f32_16x16x32_bf16(hhB, WhH[g], aB[g], 0, 0, 0);     \
        _Pragma("unroll") for (int g = 0; g < 4; ++g)                                         \
            aA[g] = __builtin_amdgcn_mfma_f32_16x16x32_bf16(hhA, WhL[g], aA[g], 0, 0, 0);     \
        _Pragma("unroll") for (int g = 0; g < 4; ++g)                                         \
            aB[g] = __builtin_amdgcn_mfma_f32_16x16x32_bf16(hhB, WhL[g], aB[g], 0, 0, 0);     \
        _Pragma("unroll") for (int g = 0; g < 4; ++g)                                         \
            aA[g] = __builtin_amdgcn_mfma_f32_16x16x32_bf16(hlA, WhH[g], aA[g], 0, 0, 0);     \
        _Pragma("unroll") for (int g = 0; g < 4; ++g)                                         \
            aB[g] = __builtin_amdgcn_mfma_f32_16x16x32_bf16(hlB, WhH[g], aB[g], 0, 0, 0);     \
        __builtin_amdgcn_s_setprio(0);                                                        \
        OWN_XG2((P) ^ 1, (TT) + 1); /* xg(t+1) both groups; overlaps MFMA latency */          \
        _Pragma("unroll") for (int r = 0; r < 4; ++r) {                                       \
            const float ig = sg(aA[0][r]);                                                    \
            const float fg = sg(aA[1][r]);                                                    \
            const float gg = fmaf(sg(aA[2][r]), 2.0f, -1.0f);                                 \
            const float og = sg(aA[3][r]);                                                    \
            cA[r] = fmaf(fg, cA[r], ig * gg);                                                 \
            const float hv = og * tanh_f(cA[r]);                                              \
            hoA[r] = hv;                                                                      \
            short h16, l16;                                                                   \
            fsplit(hv, h16, l16);                                                             \
            hhb[(P) ^ 1][4 * q + r][16 * t1 + n] = h16;                                       \
            hlb[(P) ^ 1][4 * q + r][16 * t1 + n] = l16;                                       \
        }                                                                                     \
        _Pragma("unroll") for (int r = 0; r < 4; ++r) {                                       \
            const float ig = sg(aB[0][r]);                                                    \
            const float fg = sg(aB[1][r]);                                                    \
            const float gg = fmaf(sg(aB[2][r]), 2.0f, -1.0f);                                 \
            const float og = sg(aB[3][r]);                                                    \
            cB[r] = fmaf(fg, cB[r], ig * gg);                                                 \
            const float hv = og * tanh_f(cB[r]);                                              \
            hoB[r] = hv;                                                                      \
            short h16, l16;                                                                   \
            fsplit(hv, h16, l16);                                                             \
            hhb[(P) ^ 1][16 + 4 * q + r][16 * t1 + n] = h16;                                  \
            hlb[(P) ^ 1][16 + 4 * q + r][16 * t1 + n] = l16;                                  \
        }                                                                                     \
        __syncthreads();                                                                      \
    } while (0)

    #pragma unroll 1
    for (int t = 0; t < SEQ; t += 2) {
        LSTM_STEP2(0, t);        // reads parity 0, writes parity 1
        LSTM_STEP2(1, t + 1);    // reads parity 1, writes parity 0
    }
#undef LSTM_STEP2
#undef OWN_XG2

    // ---- FC epilogue: lane holds h(127) of unit 16t1+n for nodes 4q+r (A) and
    //      16+4q+r (B); reduce over the 16 unit-lanes (same q) via shfl ----
    float pA0 = hoA[0] * fcw, pA1 = hoA[1] * fcw, pA2 = hoA[2] * fcw, pA3 = hoA[3] * fcw;
    float pB0 = hoB[0] * fcw, pB1 = hoB[1] * fcw, pB2 = hoB[2] * fcw, pB3 = hoB[3] * fcw;
    #pragma unroll
    for (int m = 1; m < 16; m <<= 1) {
        pA0 += __shfl_xor(pA0, m);
        pA1 += __shfl_xor(pA1, m);
        pA2 += __shfl_xor(pA2, m);
        pA3 += __shfl_xor(pA3, m);
        pB0 += __shfl_xor(pB0, m);
        pB1 += __shfl_xor(pB1, m);
        pB2 += __shfl_xor(pB2, m);
        pB3 += __shfl_xor(pB3, m);
    }
    if (n == 0) {
        fcp[t1][4 * q + 0] = pA0;
        fcp[t1][4 * q + 1] = pA1;
        fcp[t1][4 * q + 2] = pA2;
        fcp[t1][4 * q + 3] = pA3;
        fcp[t1][16 + 4 * q + 0] = pB0;
        fcp[t1][16 + 4 * q + 1] = pB1;
        fcp[t1][16 + 4 * q + 2] = pB2;
        fcp[t1][16 + 4 * q + 3] = pB3;
    }
    __syncthreads();
    if (t1 == 0 && lane < 32) {
        const int node = base + lane;
        if (node < N) out[node] = fcp[0][lane] + fcp[1][lane] + fc_b[0];
    }
}

extern "C" void kernel_launch(void* const* d_in, const int* in_sizes, int n_in,
                              void* d_out, int out_size, void* d_ws, size_t ws_size,
                              hipStream_t stream) {
    const float* x     = (const float*)d_in[0];
    const int*   idx   = (const int*)d_in[1];
    const float* gcn_W = (const float*)d_in[2];
    const float* gcn_b = (const float*)d_in[3];
    const float* w_ih  = (const float*)d_in[4];
    const float* w_hh  = (const float*)d_in[5];
    const float* b_ih  = (const float*)d_in[6];
    const float* b_hh  = (const float*)d_in[7];
    const float* fc_W  = (const float*)d_in[8];
    const float* fc_b  = (const float*)d_in[9];

    const int num_nodes = in_sizes[0] / (SEQ * 2);
    const int ntot = num_nodes * SEQ;
    const int E = in_sizes[1] / 2;

    // workspace: deg[ntot i32] | aggP[ntot u64]  (3 planes of 4B)
    int* deg = (int*)d_ws;
    unsigned long long* aggP = (unsigned long long*)((char*)d_ws + (size_t)ntot * 4);

    hipMemsetAsync(d_ws, 0, (size_t)ntot * 12, stream);

    const int eb = (E + 1023) / 1024;  // 4 edges/thread, 256 threads/block
    count_kernel<<<eb, 256, 0, stream>>>(idx, E, deg);
    scatter_pk_kernel<<<eb, 256, 0, stream>>>(idx, E, (const float2*)x, deg, aggP);
    lstm_sw4_kernel<<<(num_nodes + 31) / 32, TPB2, 0, stream>>>(
        (const float2*)x, aggP, deg, num_nodes,
        gcn_W, gcn_b, w_ih, w_hh, b_ih, b_hh, fc_W, fc_b,
        (float*)d_out);
}